// Round 2
// baseline (424.343 us; speedup 1.0000x reference)
//
#include <hip/hip_runtime.h>

#define B_     16
#define D_     256
#define HEADS_ 8
#define N_     32
#define H_     56
#define W_     56
#define L_     3136
#define LDA    40   // LDS row stride (bf16 elems): 32 + 8 pad -> conflict-free b128 reads

typedef short short8 __attribute__((ext_vector_type(8)));
typedef float f32x4  __attribute__((ext_vector_type(4)));

__device__ __forceinline__ unsigned short f2bf(float f) {
    union { float f; unsigned u; } c; c.f = f;
    unsigned u = c.u;
    u += 0x7fffu + ((u >> 16) & 1u);   // RNE
    return (unsigned short)(u >> 16);
}
__device__ __forceinline__ float bf2f(unsigned short h) {
    union { unsigned u; float f; } c; c.u = ((unsigned)h) << 16;
    return c.f;
}

// ---------------------------------------------------------------------------
// x [b][c][l] fp32  ->  Xt [b][l][c] bf16   (64x64 LDS tile transpose)
// ---------------------------------------------------------------------------
__global__ __launch_bounds__(256) void transpose_x_kernel(
    const float* __restrict__ x, unsigned short* __restrict__ Xt)
{
    __shared__ float tile[64][65];
    const int bb = blockIdx.z;
    const int c0 = blockIdx.y * 64;
    const int l0 = blockIdx.x * 64;
    const int t  = threadIdx.x;
    const int g4 = (t & 15) * 4;   // 4-wide column group
    const int rr = t >> 4;         // row base 0..15

    const float* xb = x + ((size_t)bb * D_ + c0) * L_ + l0;
#pragma unroll
    for (int i = 0; i < 4; ++i) {
        const int c = rr + i * 16;
        float4 v = *(const float4*)(xb + (size_t)c * L_ + g4);
        *(float4*)&tile[c][g4] = v;
    }
    __syncthreads();
    unsigned short* Xb = Xt + ((size_t)bb * L_ + l0) * D_ + c0;
#pragma unroll
    for (int i = 0; i < 4; ++i) {
        const int l = rr + i * 16;
        uint2 o;
        o.x = (unsigned)f2bf(tile[g4 + 0][l]) | ((unsigned)f2bf(tile[g4 + 1][l]) << 16);
        o.y = (unsigned)f2bf(tile[g4 + 2][l]) | ((unsigned)f2bf(tile[g4 + 3][l]) << 16);
        *(uint2*)(Xb + (size_t)l * D_ + g4) = o;
    }
}

// ---------------------------------------------------------------------------
// Wk, Wv, Wproj fp32 -> bf16 (grid.y selects matrix)
// ---------------------------------------------------------------------------
__global__ __launch_bounds__(256) void convert_w_kernel(
    const float* __restrict__ w0, const float* __restrict__ w1,
    const float* __restrict__ w2, unsigned short* __restrict__ o0,
    unsigned short* __restrict__ o1, unsigned short* __restrict__ o2)
{
    const float* src; unsigned short* dst;
    if (blockIdx.y == 0)      { src = w0; dst = o0; }
    else if (blockIdx.y == 1) { src = w1; dst = o1; }
    else                      { src = w2; dst = o2; }
    const int i = (blockIdx.x * 256 + threadIdx.x) * 4;
    float4 v = *(const float4*)(src + i);
    uint2 o;
    o.x = (unsigned)f2bf(v.x) | ((unsigned)f2bf(v.y) << 16);
    o.y = (unsigned)f2bf(v.z) | ((unsigned)f2bf(v.w) << 16);
    *(uint2*)(dst + i) = o;
}

// ---------------------------------------------------------------------------
// K/V projection, MFMA bf16. BM=128(d) BN=64(l) BK=32, 4 waves.
// Writes V (bf16) and S = q.K (fp32, per-head) -- K is never materialized.
// Wave w covers d-rows [d0+32w, d0+32w+32) == exactly one head.
// ---------------------------------------------------------------------------
__global__ __launch_bounds__(256) void gemm_kv_mfma(
    const unsigned short* __restrict__ Xt, const unsigned short* __restrict__ Wkb,
    const unsigned short* __restrict__ Wvb, const float* __restrict__ q,
    unsigned short* __restrict__ Vo, float* __restrict__ S)
{
    __shared__ unsigned short Aks[128][LDA];
    __shared__ unsigned short Avs[128][LDA];
    __shared__ unsigned short Bs[64][LDA];

    const int bb = blockIdx.z;
    const int d0 = blockIdx.y * 128;
    const int l0 = blockIdx.x * 64;
    const int t  = threadIdx.x;
    const int w    = t >> 6;
    const int lane = t & 63;
    const int col  = lane & 15;
    const int quad = lane >> 4;

    f32x4 accK[2][4], accV[2][4];
#pragma unroll
    for (int mi = 0; mi < 2; ++mi)
#pragma unroll
        for (int ni = 0; ni < 4; ++ni) {
            accK[mi][ni] = (f32x4){0.f, 0.f, 0.f, 0.f};
            accV[mi][ni] = (f32x4){0.f, 0.f, 0.f, 0.f};
        }

    // staging geometry
    const int srow = t >> 2;            // 0..63
    const int skc  = (t & 3) * 8;       // k chunk within BK
    const unsigned short* Xrow = Xt + ((size_t)bb * L_ + l0 + srow) * D_ + skc;
    const unsigned short* Wk0  = Wkb + (size_t)(d0 + srow) * D_ + skc;
    const unsigned short* Wk1  = Wkb + (size_t)(d0 + 64 + srow) * D_ + skc;
    const unsigned short* Wv0  = Wvb + (size_t)(d0 + srow) * D_ + skc;
    const unsigned short* Wv1  = Wvb + (size_t)(d0 + 64 + srow) * D_ + skc;

    for (int kt = 0; kt < 8; ++kt) {
        const int c0 = kt * 32;
        uint4 xg  = *(const uint4*)(Xrow + c0);
        uint4 kg0 = *(const uint4*)(Wk0 + c0);
        uint4 kg1 = *(const uint4*)(Wk1 + c0);
        uint4 vg0 = *(const uint4*)(Wv0 + c0);
        uint4 vg1 = *(const uint4*)(Wv1 + c0);

        __syncthreads();
        *(uint4*)&Bs[srow][skc]        = xg;
        *(uint4*)&Aks[srow][skc]       = kg0;
        *(uint4*)&Aks[srow + 64][skc]  = kg1;
        *(uint4*)&Avs[srow][skc]       = vg0;
        *(uint4*)&Avs[srow + 64][skc]  = vg1;
        __syncthreads();

        short8 ak0 = *(const short8*)&Aks[w * 32 + col][quad * 8];
        short8 ak1 = *(const short8*)&Aks[w * 32 + 16 + col][quad * 8];
        short8 av0 = *(const short8*)&Avs[w * 32 + col][quad * 8];
        short8 av1 = *(const short8*)&Avs[w * 32 + 16 + col][quad * 8];
        short8 bfr[4];
#pragma unroll
        for (int ni = 0; ni < 4; ++ni)
            bfr[ni] = *(const short8*)&Bs[ni * 16 + col][quad * 8];

#pragma unroll
        for (int ni = 0; ni < 4; ++ni) {
            accK[0][ni] = __builtin_amdgcn_mfma_f32_16x16x32_bf16(ak0, bfr[ni], accK[0][ni], 0, 0, 0);
            accK[1][ni] = __builtin_amdgcn_mfma_f32_16x16x32_bf16(ak1, bfr[ni], accK[1][ni], 0, 0, 0);
            accV[0][ni] = __builtin_amdgcn_mfma_f32_16x16x32_bf16(av0, bfr[ni], accV[0][ni], 0, 0, 0);
            accV[1][ni] = __builtin_amdgcn_mfma_f32_16x16x32_bf16(av1, bfr[ni], accV[1][ni], 0, 0, 0);
        }
    }

    // ---- V epilogue (bf16) ----
#pragma unroll
    for (int mi = 0; mi < 2; ++mi)
#pragma unroll
        for (int ni = 0; ni < 4; ++ni)
#pragma unroll
            for (int r = 0; r < 4; ++r) {
                const int d = d0 + w * 32 + mi * 16 + quad * 4 + r;
                const int l = l0 + ni * 16 + col;
                Vo[((size_t)bb * D_ + d) * L_ + l] = f2bf(accV[mi][ni][r]);
            }

    // ---- S epilogue: S[b,h,l] = sum_n q[b,h,n] * K[b,h,n,l] ----
    const int hh = blockIdx.y * 4 + w;          // head of this wave
    float qv[2][4];
#pragma unroll
    for (int mi = 0; mi < 2; ++mi)
#pragma unroll
        for (int r = 0; r < 4; ++r)
            qv[mi][r] = q[bb * D_ + hh * N_ + mi * 16 + quad * 4 + r];

#pragma unroll
    for (int ni = 0; ni < 4; ++ni) {
        float s = 0.f;
#pragma unroll
        for (int mi = 0; mi < 2; ++mi)
#pragma unroll
            for (int r = 0; r < 4; ++r)
                s = fmaf(qv[mi][r], accK[mi][ni][r], s);
        s += __shfl_xor(s, 16, 64);
        s += __shfl_xor(s, 32, 64);
        if (lane < 16)
            S[((size_t)bb * HEADS_ + hh) * L_ + l0 + ni * 16 + col] = s;
    }
}

// ---------------------------------------------------------------------------
// attend: thread = (l, h). 9-way softmax on S, weighted V gather,
// writes Om bf16 layout [b][h][l][32] (coalesced 64 B/thread).
// ---------------------------------------------------------------------------
__global__ __launch_bounds__(256) void attend_kernel(
    const float* __restrict__ S, const unsigned short* __restrict__ Vo,
    const float* __restrict__ pos_emb, const float* __restrict__ Wlin,
    unsigned short* __restrict__ Om)
{
    const int l = blockIdx.x * 256 + threadIdx.x;
    if (l >= L_) return;
    const int h  = blockIdx.y;
    const int bb = blockIdx.z;
    const int y  = l / W_;
    const int xx = l - y * W_;

    const float scale = Wlin[0] + Wlin[1] + Wlin[2] + Wlin[3];
    const float pe0 = pos_emb[0], pe1 = pos_emb[1], pe2 = pos_emb[2];
    const float pe3 = pos_emb[3], pe4 = pos_emb[4];
    const float bias[9] = {pe0, pe1, pe2, pe1, pe2, pe3, pe2, pe3, pe4};

    int  off[9];
    bool ok[9];
#pragma unroll
    for (int dy = 0; dy < 3; ++dy)
#pragma unroll
        for (int dx = 0; dx < 3; ++dx) {
            const int k = dy * 3 + dx;
            const int r = y + dy - 1, c = xx + dx - 1;
            ok[k]  = (r >= 0 && r < H_ && c >= 0 && c < W_);
            off[k] = (dy - 1) * W_ + (dx - 1);
        }

    const float* Sb = S + ((size_t)bb * HEADS_ + h) * L_ + l;
    float lg[9], m = -1e30f;
#pragma unroll
    for (int k = 0; k < 9; ++k) {
        lg[k] = (ok[k] ? Sb[off[k]] : 0.f) + bias[k];  // padded K==0 -> logit=bias
        m = fmaxf(m, lg[k]);
    }
    float ssum = 0.f;
#pragma unroll
    for (int k = 0; k < 9; ++k) { lg[k] = __expf(lg[k] - m); ssum += lg[k]; }
    const float inv = scale / ssum;
    float wgt[9];
#pragma unroll
    for (int k = 0; k < 9; ++k) wgt[k] = lg[k] * inv;

    const unsigned short* Vb = Vo + ((size_t)bb * D_ + h * N_) * L_ + l;
    union { unsigned short hh[32]; uint4 v[4]; } om;
#pragma unroll
    for (int n = 0; n < N_; ++n) {
        const unsigned short* Vr = Vb + (size_t)n * L_;
        float a = 0.f;
#pragma unroll
        for (int k = 0; k < 9; ++k)
            a = fmaf(wgt[k], ok[k] ? bf2f(Vr[off[k]]) : 0.f, a);
        om.hh[n] = f2bf(a);
    }
    unsigned short* dst = Om + (((size_t)bb * HEADS_ + h) * L_ + l) * N_;
#pragma unroll
    for (int i = 0; i < 4; ++i) *(uint4*)(dst + i * 8) = om.v[i];
}

// ---------------------------------------------------------------------------
// out = Wproj @ Om.  B-tile k-chunk kt == head kt (BK=32), rows of Om are
// contiguous 32-bf16 runs. Same MFMA structure as gemm_kv, single output.
// ---------------------------------------------------------------------------
__global__ __launch_bounds__(256) void gemm_proj_mfma(
    const unsigned short* __restrict__ Om, const unsigned short* __restrict__ Wpb,
    float* __restrict__ Out)
{
    __shared__ unsigned short As[128][LDA];
    __shared__ unsigned short Bs[64][LDA];

    const int bb = blockIdx.z;
    const int d0 = blockIdx.y * 128;
    const int l0 = blockIdx.x * 64;
    const int t  = threadIdx.x;
    const int w    = t >> 6;
    const int lane = t & 63;
    const int col  = lane & 15;
    const int quad = lane >> 4;

    f32x4 acc[2][4];
#pragma unroll
    for (int mi = 0; mi < 2; ++mi)
#pragma unroll
        for (int ni = 0; ni < 4; ++ni) acc[mi][ni] = (f32x4){0.f, 0.f, 0.f, 0.f};

    const int srow = t >> 2;
    const int skc  = (t & 3) * 8;
    const unsigned short* Wp0 = Wpb + (size_t)(d0 + srow) * D_ + skc;
    const unsigned short* Wp1 = Wpb + (size_t)(d0 + 64 + srow) * D_ + skc;
    const unsigned short* Orow = Om + ((size_t)bb * HEADS_ * L_ + l0 + srow) * N_ + skc;

    for (int kt = 0; kt < 8; ++kt) {
        const int c0 = kt * 32;
        uint4 bg  = *(const uint4*)(Orow + (size_t)kt * L_ * N_);
        uint4 ag0 = *(const uint4*)(Wp0 + c0);
        uint4 ag1 = *(const uint4*)(Wp1 + c0);

        __syncthreads();
        *(uint4*)&Bs[srow][skc]       = bg;
        *(uint4*)&As[srow][skc]       = ag0;
        *(uint4*)&As[srow + 64][skc]  = ag1;
        __syncthreads();

        short8 a0 = *(const short8*)&As[w * 32 + col][quad * 8];
        short8 a1 = *(const short8*)&As[w * 32 + 16 + col][quad * 8];
        short8 bfr[4];
#pragma unroll
        for (int ni = 0; ni < 4; ++ni)
            bfr[ni] = *(const short8*)&Bs[ni * 16 + col][quad * 8];

#pragma unroll
        for (int ni = 0; ni < 4; ++ni) {
            acc[0][ni] = __builtin_amdgcn_mfma_f32_16x16x32_bf16(a0, bfr[ni], acc[0][ni], 0, 0, 0);
            acc[1][ni] = __builtin_amdgcn_mfma_f32_16x16x32_bf16(a1, bfr[ni], acc[1][ni], 0, 0, 0);
        }
    }

#pragma unroll
    for (int mi = 0; mi < 2; ++mi)
#pragma unroll
        for (int ni = 0; ni < 4; ++ni)
#pragma unroll
            for (int r = 0; r < 4; ++r) {
                const int d = d0 + w * 32 + mi * 16 + quad * 4 + r;
                const int l = l0 + ni * 16 + col;
                Out[((size_t)bb * D_ + d) * L_ + l] = acc[mi][ni][r];
            }
}

// ---------------------------------------------------------------------------
extern "C" void kernel_launch(void* const* d_in, const int* in_sizes, int n_in,
                              void* d_out, int out_size, void* d_ws, size_t ws_size,
                              hipStream_t stream)
{
    const float* x       = (const float*)d_in[0];
    const float* q       = (const float*)d_in[1];
    const float* Wk      = (const float*)d_in[2];
    const float* Wv      = (const float*)d_in[3];
    const float* pos_emb = (const float*)d_in[4];
    const float* Wlin    = (const float*)d_in[5];
    const float* Wproj   = (const float*)d_in[6];
    float* out = (float*)d_out;

    const size_t planeE = (size_t)B_ * D_ * L_;      // 12,845,056 elems
    unsigned short* Xt  = (unsigned short*)d_ws;
    unsigned short* Vo  = Xt + planeE;
    unsigned short* Om  = Vo + planeE;
    unsigned short* Wkb = Om + planeE;
    unsigned short* Wvb = Wkb + D_ * D_;
    unsigned short* Wpb = Wvb + D_ * D_;
    float*          S   = (float*)(Wpb + D_ * D_);   // B*8*L fp32

    transpose_x_kernel<<<dim3(L_ / 64, D_ / 64, B_), 256, 0, stream>>>(x, Xt);
    convert_w_kernel<<<dim3(64, 3), 256, 0, stream>>>(Wk, Wv, Wproj, Wkb, Wvb, Wpb);
    gemm_kv_mfma<<<dim3(L_ / 64, 2, B_), 256, 0, stream>>>(Xt, Wkb, Wvb, q, Vo, S);
    attend_kernel<<<dim3((L_ + 255) / 256, HEADS_, B_), 256, 0, stream>>>(
        S, Vo, pos_emb, Wlin, Om);
    gemm_proj_mfma<<<dim3(L_ / 64, 2, B_), 256, 0, stream>>>(Om, Wpb, out);
}

// Round 3
// 181.067 us; speedup vs baseline: 2.3436x; 2.3436x over previous
//
#include <hip/hip_runtime.h>

#define B_     16
#define D_     256
#define HEADS_ 8
#define N_     32
#define H_     56
#define W_     56
#define L_     3136
#define LDA    40   // LDS row stride (bf16 elems): 32 + 8 pad -> conflict-free b128 reads

typedef short short8 __attribute__((ext_vector_type(8)));
typedef float f32x4  __attribute__((ext_vector_type(4)));

__device__ __forceinline__ unsigned short f2bf(float f) {
    union { float f; unsigned u; } c; c.f = f;
    unsigned u = c.u;
    u += 0x7fffu + ((u >> 16) & 1u);   // RNE
    return (unsigned short)(u >> 16);
}

// ---------------------------------------------------------------------------
// x [b][c][l] fp32  ->  Xt [b][l][c] bf16   (64x64 LDS tile transpose)
// ---------------------------------------------------------------------------
__global__ __launch_bounds__(256) void transpose_x_kernel(
    const float* __restrict__ x, unsigned short* __restrict__ Xt)
{
    __shared__ float tile[64][65];
    const int bb = blockIdx.z;
    const int c0 = blockIdx.y * 64;
    const int l0 = blockIdx.x * 64;
    const int t  = threadIdx.x;
    const int g4 = (t & 15) * 4;
    const int rr = t >> 4;

    const float* xb = x + ((size_t)bb * D_ + c0) * L_ + l0;
#pragma unroll
    for (int i = 0; i < 4; ++i) {
        const int c = rr + i * 16;
        float4 v = *(const float4*)(xb + (size_t)c * L_ + g4);
        *(float4*)&tile[c][g4] = v;
    }
    __syncthreads();
    unsigned short* Xb = Xt + ((size_t)bb * L_ + l0) * D_ + c0;
#pragma unroll
    for (int i = 0; i < 4; ++i) {
        const int l = rr + i * 16;
        uint2 o;
        o.x = (unsigned)f2bf(tile[g4 + 0][l]) | ((unsigned)f2bf(tile[g4 + 1][l]) << 16);
        o.y = (unsigned)f2bf(tile[g4 + 2][l]) | ((unsigned)f2bf(tile[g4 + 3][l]) << 16);
        *(uint2*)(Xb + (size_t)l * D_ + g4) = o;
    }
}

// ---------------------------------------------------------------------------
// Wk, Wv, Wproj fp32 -> bf16
// ---------------------------------------------------------------------------
__global__ __launch_bounds__(256) void convert_w_kernel(
    const float* __restrict__ w0, const float* __restrict__ w1,
    const float* __restrict__ w2, unsigned short* __restrict__ o0,
    unsigned short* __restrict__ o1, unsigned short* __restrict__ o2)
{
    const float* src; unsigned short* dst;
    if (blockIdx.y == 0)      { src = w0; dst = o0; }
    else if (blockIdx.y == 1) { src = w1; dst = o1; }
    else                      { src = w2; dst = o2; }
    const int i = (blockIdx.x * 256 + threadIdx.x) * 4;
    float4 v = *(const float4*)(src + i);
    uint2 o;
    o.x = (unsigned)f2bf(v.x) | ((unsigned)f2bf(v.y) << 16);
    o.y = (unsigned)f2bf(v.z) | ((unsigned)f2bf(v.w) << 16);
    *(uint2*)(dst + i) = o;
}

// ---------------------------------------------------------------------------
// K/V projection, MFMA bf16. BM=128(d) BN=64(l) BK=32, 4 waves.
// Writes V (bf16) and S = q.K (fp32, per-head) -- K never materialized.
// ---------------------------------------------------------------------------
__global__ __launch_bounds__(256) void gemm_kv_mfma(
    const unsigned short* __restrict__ Xt, const unsigned short* __restrict__ Wkb,
    const unsigned short* __restrict__ Wvb, const float* __restrict__ q,
    unsigned short* __restrict__ Vo, float* __restrict__ S)
{
    __shared__ unsigned short Aks[128][LDA];
    __shared__ unsigned short Avs[128][LDA];
    __shared__ unsigned short Bs[64][LDA];

    const int bb = blockIdx.z;
    const int d0 = blockIdx.y * 128;
    const int l0 = blockIdx.x * 64;
    const int t  = threadIdx.x;
    const int w    = t >> 6;
    const int lane = t & 63;
    const int col  = lane & 15;
    const int quad = lane >> 4;

    f32x4 accK[2][4], accV[2][4];
#pragma unroll
    for (int mi = 0; mi < 2; ++mi)
#pragma unroll
        for (int ni = 0; ni < 4; ++ni) {
            accK[mi][ni] = (f32x4){0.f, 0.f, 0.f, 0.f};
            accV[mi][ni] = (f32x4){0.f, 0.f, 0.f, 0.f};
        }

    const int srow = t >> 2;
    const int skc  = (t & 3) * 8;
    const unsigned short* Xrow = Xt + ((size_t)bb * L_ + l0 + srow) * D_ + skc;
    const unsigned short* Wk0  = Wkb + (size_t)(d0 + srow) * D_ + skc;
    const unsigned short* Wk1  = Wkb + (size_t)(d0 + 64 + srow) * D_ + skc;
    const unsigned short* Wv0  = Wvb + (size_t)(d0 + srow) * D_ + skc;
    const unsigned short* Wv1  = Wvb + (size_t)(d0 + 64 + srow) * D_ + skc;

    for (int kt = 0; kt < 8; ++kt) {
        const int c0 = kt * 32;
        uint4 xg  = *(const uint4*)(Xrow + c0);
        uint4 kg0 = *(const uint4*)(Wk0 + c0);
        uint4 kg1 = *(const uint4*)(Wk1 + c0);
        uint4 vg0 = *(const uint4*)(Wv0 + c0);
        uint4 vg1 = *(const uint4*)(Wv1 + c0);

        __syncthreads();
        *(uint4*)&Bs[srow][skc]        = xg;
        *(uint4*)&Aks[srow][skc]       = kg0;
        *(uint4*)&Aks[srow + 64][skc]  = kg1;
        *(uint4*)&Avs[srow][skc]       = vg0;
        *(uint4*)&Avs[srow + 64][skc]  = vg1;
        __syncthreads();

        short8 ak0 = *(const short8*)&Aks[w * 32 + col][quad * 8];
        short8 ak1 = *(const short8*)&Aks[w * 32 + 16 + col][quad * 8];
        short8 av0 = *(const short8*)&Avs[w * 32 + col][quad * 8];
        short8 av1 = *(const short8*)&Avs[w * 32 + 16 + col][quad * 8];
        short8 bfr[4];
#pragma unroll
        for (int ni = 0; ni < 4; ++ni)
            bfr[ni] = *(const short8*)&Bs[ni * 16 + col][quad * 8];

#pragma unroll
        for (int ni = 0; ni < 4; ++ni) {
            accK[0][ni] = __builtin_amdgcn_mfma_f32_16x16x32_bf16(ak0, bfr[ni], accK[0][ni], 0, 0, 0);
            accK[1][ni] = __builtin_amdgcn_mfma_f32_16x16x32_bf16(ak1, bfr[ni], accK[1][ni], 0, 0, 0);
            accV[0][ni] = __builtin_amdgcn_mfma_f32_16x16x32_bf16(av0, bfr[ni], accV[0][ni], 0, 0, 0);
            accV[1][ni] = __builtin_amdgcn_mfma_f32_16x16x32_bf16(av1, bfr[ni], accV[1][ni], 0, 0, 0);
        }
    }

    // ---- V epilogue (bf16) ----
#pragma unroll
    for (int mi = 0; mi < 2; ++mi)
#pragma unroll
        for (int ni = 0; ni < 4; ++ni)
#pragma unroll
            for (int r = 0; r < 4; ++r) {
                const int d = d0 + w * 32 + mi * 16 + quad * 4 + r;
                const int l = l0 + ni * 16 + col;
                Vo[((size_t)bb * D_ + d) * L_ + l] = f2bf(accV[mi][ni][r]);
            }

    // ---- S epilogue: S[b,h,l] = q . K ----
    const int hh = blockIdx.y * 4 + w;
    float qv[2][4];
#pragma unroll
    for (int mi = 0; mi < 2; ++mi)
#pragma unroll
        for (int r = 0; r < 4; ++r)
            qv[mi][r] = q[bb * D_ + hh * N_ + mi * 16 + quad * 4 + r];

#pragma unroll
    for (int ni = 0; ni < 4; ++ni) {
        float s = 0.f;
#pragma unroll
        for (int mi = 0; mi < 2; ++mi)
#pragma unroll
            for (int r = 0; r < 4; ++r)
                s = fmaf(qv[mi][r], accK[mi][ni][r], s);
        s += __shfl_xor(s, 16, 64);
        s += __shfl_xor(s, 32, 64);
        if (lane < 16)
            S[((size_t)bb * HEADS_ + hh) * L_ + l0 + ni * 16 + col] = s;
    }
}

// ---------------------------------------------------------------------------
// attend v3: LDS-staged. Block = (8-row band, 8-ch group, b*h).
// Vs transposed to [row][col][ch] so each tap is one aligned ds_read_b128
// with 16B lane stride (conflict-free). Zero halo == padded K/V semantics.
// ---------------------------------------------------------------------------
__global__ __launch_bounds__(256) void attend_kernel(
    const float* __restrict__ S, const unsigned short* __restrict__ Vo,
    const float* __restrict__ pos_emb, const float* __restrict__ Wlin,
    unsigned short* __restrict__ Om)
{
    __shared__ unsigned short Vs[10][60][8];   // 9.6 KB
    __shared__ float Ss[10][58];               // 2.3 KB

    const int band = blockIdx.x;   // 0..6  (8 image rows each)
    const int half = blockIdx.y;   // 0..3  (8-channel group)
    const int bh   = blockIdx.z;   // 0..127
    const int y0   = band * 8;
    const int t    = threadIdx.x;

    // ---- stage S (10 x 58, zero halo) ----
    const float* Sb = S + (size_t)bh * L_;
    for (int wi = t; wi < 580; wi += 256) {
        const int row = wi / 58, c = wi - row * 58;
        const int gr = y0 - 1 + row, gc = c - 1;
        float v = 0.f;
        if (gr >= 0 && gr < H_ && gc >= 0 && gc < W_)
            v = Sb[gr * W_ + gc];
        Ss[row][c] = v;
    }

    // ---- stage V (transpose to [row][col][ch], zero halo rows) ----
    const unsigned short* Vbase = Vo + ((size_t)bh * N_ + half * 8) * L_;
    for (int j = t; j < 560; j += 256) {
        const int ch = j & 7;
        const int rr = j >> 3;              // 0..69
        const int row = rr / 7, cg = rr - row * 7;
        const int gr = y0 - 1 + row;
        uint4 v = make_uint4(0u, 0u, 0u, 0u);
        if (gr >= 0 && gr < H_)
            v = *(const uint4*)(Vbase + (size_t)ch * L_ + gr * W_ + cg * 8);
        const unsigned short* hw = (const unsigned short*)&v;
        const int colb = cg * 8 + 1;
#pragma unroll
        for (int i = 0; i < 8; ++i)
            Vs[row][colb + i][ch] = hw[i];
    }
    // zero edge cols 0 and 57
    if (t < 160) {
        const int row = t >> 4, side = (t >> 3) & 1, ch = t & 7;
        Vs[row][side ? 57 : 0][ch] = 0;
    }
    __syncthreads();

    const float scale = Wlin[0] + Wlin[1] + Wlin[2] + Wlin[3];
    const float pe0 = pos_emb[0], pe1 = pos_emb[1], pe2 = pos_emb[2];
    const float pe3 = pos_emb[3], pe4 = pos_emb[4];
    const float bias[9] = {pe0, pe1, pe2, pe1, pe2, pe3, pe2, pe3, pe4};

    for (int p = t; p < 448; p += 256) {
        const int yl = p / 56, xx = p - yl * 56;
        const int lr = yl + 1, lc = xx + 1;

        float lg[9], m = -1e30f;
#pragma unroll
        for (int dy = 0; dy < 3; ++dy)
#pragma unroll
            for (int dx = 0; dx < 3; ++dx) {
                const int k = dy * 3 + dx;
                lg[k] = Ss[lr - 1 + dy][lc - 1 + dx] + bias[k];
                m = fmaxf(m, lg[k]);
            }
        float ssum = 0.f;
#pragma unroll
        for (int k = 0; k < 9; ++k) { lg[k] = __expf(lg[k] - m); ssum += lg[k]; }
        const float inv = scale / ssum;

        float om[8] = {0.f, 0.f, 0.f, 0.f, 0.f, 0.f, 0.f, 0.f};
#pragma unroll
        for (int dy = 0; dy < 3; ++dy)
#pragma unroll
            for (int dx = 0; dx < 3; ++dx) {
                const float wk = lg[dy * 3 + dx] * inv;
                const uint4 v = *(const uint4*)&Vs[lr - 1 + dy][lc - 1 + dx][0];
                const unsigned* u = (const unsigned*)&v;
#pragma unroll
                for (int i = 0; i < 4; ++i) {
                    union { unsigned uu; float f; } lo, hi;
                    lo.uu = u[i] << 16;
                    hi.uu = u[i] & 0xffff0000u;
                    om[2 * i]     = fmaf(wk, lo.f, om[2 * i]);
                    om[2 * i + 1] = fmaf(wk, hi.f, om[2 * i + 1]);
                }
            }

        unsigned short ob[8];
#pragma unroll
        for (int i = 0; i < 8; ++i) ob[i] = f2bf(om[i]);
        const int l = (y0 + yl) * W_ + xx;
        *(uint4*)(Om + ((size_t)bh * L_ + l) * N_ + half * 8) = *(const uint4*)ob;
    }
}

// ---------------------------------------------------------------------------
// out = Wproj @ Om  (Om layout [b][h][l][32], head == K-chunk)
// ---------------------------------------------------------------------------
__global__ __launch_bounds__(256) void gemm_proj_mfma(
    const unsigned short* __restrict__ Om, const unsigned short* __restrict__ Wpb,
    float* __restrict__ Out)
{
    __shared__ unsigned short As[128][LDA];
    __shared__ unsigned short Bs[64][LDA];

    const int bb = blockIdx.z;
    const int d0 = blockIdx.y * 128;
    const int l0 = blockIdx.x * 64;
    const int t  = threadIdx.x;
    const int w    = t >> 6;
    const int lane = t & 63;
    const int col  = lane & 15;
    const int quad = lane >> 4;

    f32x4 acc[2][4];
#pragma unroll
    for (int mi = 0; mi < 2; ++mi)
#pragma unroll
        for (int ni = 0; ni < 4; ++ni) acc[mi][ni] = (f32x4){0.f, 0.f, 0.f, 0.f};

    const int srow = t >> 2;
    const int skc  = (t & 3) * 8;
    const unsigned short* Wp0 = Wpb + (size_t)(d0 + srow) * D_ + skc;
    const unsigned short* Wp1 = Wpb + (size_t)(d0 + 64 + srow) * D_ + skc;
    const unsigned short* Orow = Om + ((size_t)bb * HEADS_ * L_ + l0 + srow) * N_ + skc;

    for (int kt = 0; kt < 8; ++kt) {
        const int c0 = kt * 32;
        uint4 bg  = *(const uint4*)(Orow + (size_t)kt * L_ * N_);
        uint4 ag0 = *(const uint4*)(Wp0 + c0);
        uint4 ag1 = *(const uint4*)(Wp1 + c0);

        __syncthreads();
        *(uint4*)&Bs[srow][skc]       = bg;
        *(uint4*)&As[srow][skc]       = ag0;
        *(uint4*)&As[srow + 64][skc]  = ag1;
        __syncthreads();

        short8 a0 = *(const short8*)&As[w * 32 + col][quad * 8];
        short8 a1 = *(const short8*)&As[w * 32 + 16 + col][quad * 8];
        short8 bfr[4];
#pragma unroll
        for (int ni = 0; ni < 4; ++ni)
            bfr[ni] = *(const short8*)&Bs[ni * 16 + col][quad * 8];

#pragma unroll
        for (int ni = 0; ni < 4; ++ni) {
            acc[0][ni] = __builtin_amdgcn_mfma_f32_16x16x32_bf16(a0, bfr[ni], acc[0][ni], 0, 0, 0);
            acc[1][ni] = __builtin_amdgcn_mfma_f32_16x16x32_bf16(a1, bfr[ni], acc[1][ni], 0, 0, 0);
        }
    }

#pragma unroll
    for (int mi = 0; mi < 2; ++mi)
#pragma unroll
        for (int ni = 0; ni < 4; ++ni)
#pragma unroll
            for (int r = 0; r < 4; ++r) {
                const int d = d0 + w * 32 + mi * 16 + quad * 4 + r;
                const int l = l0 + ni * 16 + col;
                Out[((size_t)bb * D_ + d) * L_ + l] = acc[mi][ni][r];
            }
}

// ---------------------------------------------------------------------------
extern "C" void kernel_launch(void* const* d_in, const int* in_sizes, int n_in,
                              void* d_out, int out_size, void* d_ws, size_t ws_size,
                              hipStream_t stream)
{
    const float* x       = (const float*)d_in[0];
    const float* q       = (const float*)d_in[1];
    const float* Wk      = (const float*)d_in[2];
    const float* Wv      = (const float*)d_in[3];
    const float* pos_emb = (const float*)d_in[4];
    const float* Wlin    = (const float*)d_in[5];
    const float* Wproj   = (const float*)d_in[6];
    float* out = (float*)d_out;

    const size_t planeE = (size_t)B_ * D_ * L_;
    unsigned short* Xt  = (unsigned short*)d_ws;
    unsigned short* Vo  = Xt + planeE;
    unsigned short* Om  = Vo + planeE;
    unsigned short* Wkb = Om + planeE;
    unsigned short* Wvb = Wkb + D_ * D_;
    unsigned short* Wpb = Wvb + D_ * D_;
    float*          S   = (float*)(Wpb + D_ * D_);

    transpose_x_kernel<<<dim3(L_ / 64, D_ / 64, B_), 256, 0, stream>>>(x, Xt);
    convert_w_kernel<<<dim3(64, 3), 256, 0, stream>>>(Wk, Wv, Wproj, Wkb, Wvb, Wpb);
    gemm_kv_mfma<<<dim3(L_ / 64, 2, B_), 256, 0, stream>>>(Xt, Wkb, Wvb, q, Vo, S);
    attend_kernel<<<dim3(7, 4, B_ * HEADS_), 256, 0, stream>>>(
        S, Vo, pos_emb, Wlin, Om);
    gemm_proj_mfma<<<dim3(L_ / 64, 2, B_), 256, 0, stream>>>(Om, Wpb, out);
}